// Round 1
// baseline (343.579 us; speedup 1.0000x reference)
//
#include <hip/hip_runtime.h>

#define NB 32
#define NC 1024
#define NT 512
#define NO 1024

typedef __attribute__((ext_vector_type(8))) short bf16x8;
typedef __attribute__((ext_vector_type(4))) float f32x4;

__device__ __forceinline__ unsigned short f2bf(float f){
  unsigned int i = __float_as_uint(f);
  i += 0x7fffu + ((i >> 16) & 1u);
  return (unsigned short)(i >> 16);
}

__device__ __forceinline__ unsigned int blend_pack(unsigned int u0, unsigned int u1, float t){
  float a0 = __uint_as_float(u0 << 16);
  float a1 = __uint_as_float(u0 & 0xffff0000u);
  float b0 = __uint_as_float(u1 << 16);
  float b1 = __uint_as_float(u1 & 0xffff0000u);
  float r0 = fmaf(t, b0 - a0, a0);
  float r1 = fmaf(t, b1 - a1, a1);
  return (unsigned int)f2bf(r0) | (((unsigned int)f2bf(r1)) << 16);
}

__device__ __forceinline__ void async16(const void* g, void* l){
  __builtin_amdgcn_global_load_lds((const __attribute__((address_space(1))) void*)g,
                                   (__attribute__((address_space(3))) void*)l, 16, 0, 0);
}

// ---- transpose: x (B,C,T) f32 -> atr (B,T,C) bf16 ----
__global__ __launch_bounds__(256) void transpose_kernel(const float* __restrict__ x,
                                                        unsigned short* __restrict__ atr){
  __shared__ float tile[64][65];
  int b = blockIdx.z, c0 = blockIdx.y * 64, t0 = blockIdx.x * 64;
  int tx = threadIdx.x & 63, wy = threadIdx.x >> 6;
  const float* xp = x + ((size_t)b * NC + c0) * NT + t0;
  #pragma unroll
  for (int i = 0; i < 16; i++){ int cl = wy * 16 + i; tile[cl][tx] = xp[(size_t)cl * NT + tx]; }
  __syncthreads();
  int p = threadIdx.x & 31, r = threadIdx.x >> 5;
  unsigned int* dst = (unsigned int*)(atr + ((size_t)b * NT + t0) * NC + c0);
  #pragma unroll
  for (int i = 0; i < 8; i++){
    int tl = r * 8 + i;
    unsigned int lo = f2bf(tile[2 * p][tl]);
    unsigned int hi = f2bf(tile[2 * p + 1][tl]);
    dst[(size_t)tl * (NC / 2) + p] = lo | (hi << 16);
  }
}

// ---- offset conv (fp32) + grid-sample index/weight precompute ----
__global__ __launch_bounds__(256) void offsets_kernel(const float* __restrict__ x,
    const float* __restrict__ w_off, const float* __restrict__ b_off,
    int* __restrict__ i0a, int* __restrict__ i1a, float* __restrict__ tya){
  __shared__ float red[4][64][3];
  int b = blockIdx.y, t0 = blockIdx.x * 64;
  int tl = threadIdx.x & 63, cs = threadIdx.x >> 6;
  int t = t0 + tl;
  const float* xb = x + (size_t)b * NC * NT;
  float a0 = 0.f, a1 = 0.f, a2 = 0.f;
  for (int c = cs * 256; c < (cs + 1) * 256; ++c){
    const float* xr = xb + (size_t)c * NT;
    float xm = (t > 0)      ? xr[t - 1] : 0.f;
    float xc = xr[t];
    float xq = (t < NT - 1) ? xr[t + 1] : 0.f;
    const float* wr = w_off + (size_t)c * 3;
    a0 += xm * wr[0]    + xc * wr[1]    + xq * wr[2];
    a1 += xm * wr[3072] + xc * wr[3073] + xq * wr[3074];
    a2 += xm * wr[6144] + xc * wr[6145] + xq * wr[6146];
  }
  red[cs][tl][0] = a0; red[cs][tl][1] = a1; red[cs][tl][2] = a2;
  __syncthreads();
  if (threadIdx.x < 64){
    int tt = t0 + (int)threadIdx.x;
    #pragma unroll
    for (int o = 0; o < 3; o++){
      float p = red[0][threadIdx.x][o] + red[1][threadIdx.x][o] +
                red[2][threadIdx.x][o] + red[3][threadIdx.x][o] + b_off[o];
      float base = (float)tt / 511.0f * 2.0f - 1.0f;
      float g = base + (float)(o - 1) * (float)(2.0 / 511.0) + p;
      g = fminf(1.0f, fmaxf(-1.0f, g));
      float py = ((g + 1.0f) * 512.0f - 1.0f) * 0.5f;
      float y0 = floorf(py);
      float tyv = py - y0;
      int i0 = (int)y0;
      int i0c = min(max(i0, 0), NT - 1);
      int i1c = min(max(i0 + 1, 0), NT - 1);
      int m = b * NT + tt;
      i0a[m * 3 + o] = i0c; i1a[m * 3 + o] = i1c; tya[m * 3 + o] = tyv;
    }
  }
}

// ---- fold the data-independent x-blend into the conv weights:
// wm[k][o][c] = sum_w [ (x0c(w)==c)(1-tx) + (x1c(w)==c)tx ] * w_conv[o][w][k]  (bf16)
__global__ __launch_bounds__(256) void wmix_kernel(const float* __restrict__ w_conv,
                                                   unsigned short* __restrict__ wm){
  int gid = blockIdx.x * 256 + threadIdx.x;
  int o = gid >> 10, c = gid & 1023;
  const float ratio = (float)(1024.0 / 1023.0);
  float acc0 = 0.f, acc1 = 0.f, acc2 = 0.f;
  int wlo = (c > 2) ? c - 2 : 0;
  int whi = (c < 1021) ? c + 2 : 1023;
  for (int w = wlo; w <= whi; ++w){
    float px = (float)w * ratio - 0.5f;
    float x0 = floorf(px);
    float tx = px - x0;
    int i0 = (int)x0;
    int i0c = min(max(i0, 0), 1023);
    int i1c = min(max(i0 + 1, 0), 1023);
    float s = ((i0c == c) ? (1.0f - tx) : 0.f) + ((i1c == c) ? tx : 0.f);
    if (s != 0.f){
      const float* wc = w_conv + ((size_t)o * 1024 + w) * 3;
      acc0 += s * wc[0]; acc1 += s * wc[1]; acc2 += s * wc[2];
    }
  }
  size_t oc = (size_t)o * 1024 + c;
  wm[oc] = f2bf(acc0);
  wm[1024u * 1024u + oc] = f2bf(acc1);
  wm[2u * 1024u * 1024u + oc] = f2bf(acc2);
}

// ---- fused gather-blend GEMM: out[m][o] = sum_k sum_c Ablend_k[m][c] * wm[k][o][c] + b_conv[o]
__global__ __launch_bounds__(256) void gemm_kernel(
    const unsigned short* __restrict__ atr, const unsigned short* __restrict__ wm,
    const int* __restrict__ i0a, const int* __restrict__ i1a, const float* __restrict__ tya,
    const float* __restrict__ b_conv, float* __restrict__ out){
  __shared__ __align__(16) unsigned short As[128 * 64];
  __shared__ __align__(16) unsigned short Bs[128 * 64];

  int wg = blockIdx.x;
  int swz = (wg & 7) * 128 + (wg >> 3);       // 1024 % 8 == 0: bijective XCD swizzle
  int ntile = swz & 7, mtile = swz >> 3;
  int m0 = mtile * 128, n0 = ntile * 128;
  int b = m0 >> 9;                            // BM=128 divides T=512: single b per block
  int tid = threadIdx.x;
  int lane = tid & 63, wv = tid >> 6;
  int wr = wv >> 1, wc = wv & 1;
  int arow = tid >> 3, aseg = tid & 7;

  f32x4 acc[4][4];
  #pragma unroll
  for (int i = 0; i < 4; i++)
    #pragma unroll
    for (int j = 0; j < 4; j++) acc[i][j] = (f32x4){0.f, 0.f, 0.f, 0.f};

  const size_t atrb = (size_t)b * NT * NC;

  for (int k = 0; k < 3; k++){
    const unsigned short* s0[4]; const unsigned short* s1[4]; float tw[4];
    #pragma unroll
    for (int q = 0; q < 4; q++){
      int m = m0 + q * 32 + arow;
      int idx = m * 3 + k;
      s0[q] = atr + atrb + (size_t)i0a[idx] * NC + aseg * 8;
      s1[q] = atr + atrb + (size_t)i1a[idx] * NC + aseg * 8;
      tw[q] = tya[idx];
    }
    const unsigned short* wkb = wm + (size_t)k * 1024 * 1024 + (size_t)n0 * 1024;

    for (int c0 = 0; c0 < 1024; c0 += 64){
      // B tile [128 o][64 c] via global_load_lds (wave-uniform LDS base, lane*16B)
      #pragma unroll
      for (int it = 0; it < 4; ++it){
        int chunk = it * 4 + wv;
        int brow = chunk * 8 + (lane >> 3);
        const unsigned short* g = wkb + (size_t)brow * 1024 + c0 + (lane & 7) * 8;
        async16(g, (char*)Bs + chunk * 1024);
      }
      // A tile [128 m][64 c]: gather 2 rows + ty-blend, pack bf16, ds_write_b128
      #pragma unroll
      for (int q = 0; q < 4; q++){
        uint4 v0 = *(const uint4*)(s0[q] + c0);
        uint4 v1 = *(const uint4*)(s1[q] + c0);
        float t = tw[q];
        uint4 rv;
        rv.x = blend_pack(v0.x, v1.x, t);
        rv.y = blend_pack(v0.y, v1.y, t);
        rv.z = blend_pack(v0.z, v1.z, t);
        rv.w = blend_pack(v0.w, v1.w, t);
        *(uint4*)&As[(q * 32 + arow) * 64 + aseg * 8] = rv;
      }
      __syncthreads();
      #pragma unroll
      for (int kk = 0; kk < 2; ++kk){
        int ko = kk * 32 + (lane >> 4) * 8;
        bf16x8 af[4], bfr[4];
        #pragma unroll
        for (int mi = 0; mi < 4; mi++)
          af[mi] = *(const bf16x8*)&As[(wr * 64 + mi * 16 + (lane & 15)) * 64 + ko];
        #pragma unroll
        for (int ni = 0; ni < 4; ni++)
          bfr[ni] = *(const bf16x8*)&Bs[(wc * 64 + ni * 16 + (lane & 15)) * 64 + ko];
        #pragma unroll
        for (int mi = 0; mi < 4; mi++)
          #pragma unroll
          for (int ni = 0; ni < 4; ni++)
            acc[mi][ni] = __builtin_amdgcn_mfma_f32_16x16x32_bf16(af[mi], bfr[ni], acc[mi][ni], 0, 0, 0);
      }
      __syncthreads();
    }
  }
  // epilogue: C/D layout col=lane&15, row=(lane>>4)*4+j (m89-verified)
  #pragma unroll
  for (int ni = 0; ni < 4; ni++){
    int n = n0 + wc * 64 + ni * 16 + (lane & 15);
    float bc = b_conv[n];
    #pragma unroll
    for (int mi = 0; mi < 4; mi++){
      int mr = m0 + wr * 64 + mi * 16 + (lane >> 4) * 4;
      f32x4 v = acc[mi][ni];
      #pragma unroll
      for (int j = 0; j < 4; j++)
        out[(size_t)(mr + j) * NO + n] = v[j] + bc;
    }
  }
}

extern "C" void kernel_launch(void* const* d_in, const int* in_sizes, int n_in,
                              void* d_out, int out_size, void* d_ws, size_t ws_size,
                              hipStream_t stream){
  (void)in_sizes; (void)n_in; (void)out_size; (void)ws_size;
  const float* x      = (const float*)d_in[0];
  const float* w_off  = (const float*)d_in[1];
  const float* b_off  = (const float*)d_in[2];
  const float* w_conv = (const float*)d_in[3];
  const float* b_conv = (const float*)d_in[4];
  float* out = (float*)d_out;

  char* ws = (char*)d_ws;
  unsigned short* atr = (unsigned short*)ws;                       // 32 MB  (B,T,C) bf16
  unsigned short* wm  = (unsigned short*)(ws + 33554432);          // 6 MB   (k,o,c) bf16
  int*   i0a = (int*)  (ws + 33554432 + 6291456);                  // 768 KB idx/ty
  int*   i1a = (int*)  ((char*)i0a + 196608);
  float* tya = (float*)((char*)i1a + 196608);

  hipLaunchKernelGGL(transpose_kernel, dim3(NT / 64, NC / 64, NB), dim3(256), 0, stream, x, atr);
  hipLaunchKernelGGL(offsets_kernel,  dim3(NT / 64, NB),          dim3(256), 0, stream,
                     x, w_off, b_off, i0a, i1a, tya);
  hipLaunchKernelGGL(wmix_kernel,     dim3((1024 * 1024) / 256),  dim3(256), 0, stream, w_conv, wm);
  hipLaunchKernelGGL(gemm_kernel,     dim3((16384 / 128) * (1024 / 128)), dim3(256), 0, stream,
                     atr, wm, i0a, i1a, tya, b_conv, out);
}

// Round 2
// 280.803 us; speedup vs baseline: 1.2236x; 1.2236x over previous
//
#include <hip/hip_runtime.h>

#define NB 32
#define NC 1024
#define NT 512
#define NO 1024

typedef __attribute__((ext_vector_type(8))) short bf16x8;
typedef __attribute__((ext_vector_type(4))) float f32x4;

__device__ __forceinline__ unsigned short f2bf(float f){
  unsigned int i = __float_as_uint(f);
  i += 0x7fffu + ((i >> 16) & 1u);
  return (unsigned short)(i >> 16);
}

__device__ __forceinline__ unsigned int blend_pack(unsigned int u0, unsigned int u1, float t){
  float a0 = __uint_as_float(u0 << 16);
  float a1 = __uint_as_float(u0 & 0xffff0000u);
  float b0 = __uint_as_float(u1 << 16);
  float b1 = __uint_as_float(u1 & 0xffff0000u);
  float r0 = fmaf(t, b0 - a0, a0);
  float r1 = fmaf(t, b1 - a1, a1);
  return (unsigned int)f2bf(r0) | (((unsigned int)f2bf(r1)) << 16);
}

__device__ __forceinline__ void async16(const void* g, void* l){
  __builtin_amdgcn_global_load_lds((const __attribute__((address_space(1))) void*)g,
                                   (__attribute__((address_space(3))) void*)l, 16, 0, 0);
}

// ---- transpose: x (B,C,T) f32 -> atr (B,T,C) bf16 ----
__global__ __launch_bounds__(256) void transpose_kernel(const float* __restrict__ x,
                                                        unsigned short* __restrict__ atr){
  __shared__ float tile[64][65];
  int b = blockIdx.z, c0 = blockIdx.y * 64, t0 = blockIdx.x * 64;
  int tx = threadIdx.x & 63, wy = threadIdx.x >> 6;
  const float* xp = x + ((size_t)b * NC + c0) * NT + t0;
  #pragma unroll
  for (int i = 0; i < 16; i++){ int cl = wy * 16 + i; tile[cl][tx] = xp[(size_t)cl * NT + tx]; }
  __syncthreads();
  int p = threadIdx.x & 31, r = threadIdx.x >> 5;
  unsigned int* dst = (unsigned int*)(atr + ((size_t)b * NT + t0) * NC + c0);
  #pragma unroll
  for (int i = 0; i < 8; i++){
    int tl = r * 8 + i;
    unsigned int lo = f2bf(tile[2 * p][tl]);
    unsigned int hi = f2bf(tile[2 * p + 1][tl]);
    dst[(size_t)tl * (NC / 2) + p] = lo | (hi << 16);
  }
}

// ---- offset conv (fp32) + grid-sample index/weight precompute ----
__global__ __launch_bounds__(256) void offsets_kernel(const float* __restrict__ x,
    const float* __restrict__ w_off, const float* __restrict__ b_off,
    int* __restrict__ i0a, int* __restrict__ i1a, float* __restrict__ tya){
  __shared__ float red[4][64][3];
  int b = blockIdx.y, t0 = blockIdx.x * 64;
  int tl = threadIdx.x & 63, cs = threadIdx.x >> 6;
  int t = t0 + tl;
  const float* xb = x + (size_t)b * NC * NT;
  float a0 = 0.f, a1 = 0.f, a2 = 0.f;
  for (int c = cs * 256; c < (cs + 1) * 256; ++c){
    const float* xr = xb + (size_t)c * NT;
    float xm = (t > 0)      ? xr[t - 1] : 0.f;
    float xc = xr[t];
    float xq = (t < NT - 1) ? xr[t + 1] : 0.f;
    const float* wr = w_off + (size_t)c * 3;
    a0 += xm * wr[0]    + xc * wr[1]    + xq * wr[2];
    a1 += xm * wr[3072] + xc * wr[3073] + xq * wr[3074];
    a2 += xm * wr[6144] + xc * wr[6145] + xq * wr[6146];
  }
  red[cs][tl][0] = a0; red[cs][tl][1] = a1; red[cs][tl][2] = a2;
  __syncthreads();
  if (threadIdx.x < 64){
    int tt = t0 + (int)threadIdx.x;
    #pragma unroll
    for (int o = 0; o < 3; o++){
      float p = red[0][threadIdx.x][o] + red[1][threadIdx.x][o] +
                red[2][threadIdx.x][o] + red[3][threadIdx.x][o] + b_off[o];
      float base = (float)tt / 511.0f * 2.0f - 1.0f;
      float g = base + (float)(o - 1) * (float)(2.0 / 511.0) + p;
      g = fminf(1.0f, fmaxf(-1.0f, g));
      float py = ((g + 1.0f) * 512.0f - 1.0f) * 0.5f;
      float y0 = floorf(py);
      float tyv = py - y0;
      int i0 = (int)y0;
      int i0c = min(max(i0, 0), NT - 1);
      int i1c = min(max(i0 + 1, 0), NT - 1);
      int m = b * NT + tt;
      i0a[m * 3 + o] = i0c; i1a[m * 3 + o] = i1c; tya[m * 3 + o] = tyv;
    }
  }
}

// ---- fold data-independent x-blend into weights: wm2[o][k*1024+c] (bf16, LDK=3072) ----
__global__ __launch_bounds__(256) void wmix_kernel(const float* __restrict__ w_conv,
                                                   unsigned short* __restrict__ wm2){
  int gid = blockIdx.x * 256 + threadIdx.x;
  int o = gid >> 10, c = gid & 1023;
  const float ratio = (float)(1024.0 / 1023.0);
  float acc0 = 0.f, acc1 = 0.f, acc2 = 0.f;
  int wlo = (c > 2) ? c - 2 : 0;
  int whi = (c < 1021) ? c + 2 : 1023;
  for (int w = wlo; w <= whi; ++w){
    float px = (float)w * ratio - 0.5f;
    float x0 = floorf(px);
    float tx = px - x0;
    int i0 = (int)x0;
    int i0c = min(max(i0, 0), 1023);
    int i1c = min(max(i0 + 1, 0), 1023);
    float s = ((i0c == c) ? (1.0f - tx) : 0.f) + ((i1c == c) ? tx : 0.f);
    if (s != 0.f){
      const float* wc = w_conv + ((size_t)o * 1024 + w) * 3;
      acc0 += s * wc[0]; acc1 += s * wc[1]; acc2 += s * wc[2];
    }
  }
  size_t base = (size_t)o * 3072 + c;
  wm2[base]        = f2bf(acc0);
  wm2[base + 1024] = f2bf(acc1);
  wm2[base + 2048] = f2bf(acc2);
}

// ---- materialize blended A: Abl[m][k*1024+c] bf16 (96 MB) ----
__global__ __launch_bounds__(256) void blend_kernel(
    const unsigned short* __restrict__ atr, const int* __restrict__ i0a,
    const int* __restrict__ i1a, const float* __restrict__ tya,
    unsigned short* __restrict__ Abl){
  int k = blockIdx.y;
  int row = blockIdx.x * 2 + (threadIdx.x >> 7);
  int seg = threadIdx.x & 127;
  int idx = row * 3 + k;
  int b = row >> 9;
  const unsigned short* base = atr + (size_t)b * NT * NC;
  const uint4* r0 = (const uint4*)(base + (size_t)i0a[idx] * NC);
  const uint4* r1 = (const uint4*)(base + (size_t)i1a[idx] * NC);
  float t = tya[idx];
  uint4 v0 = r0[seg], v1 = r1[seg], rv;
  rv.x = blend_pack(v0.x, v1.x, t);
  rv.y = blend_pack(v0.y, v1.y, t);
  rv.z = blend_pack(v0.z, v1.z, t);
  rv.w = blend_pack(v0.w, v1.w, t);
  *(uint4*)(Abl + (size_t)row * 3072 + (size_t)k * 1024 + (size_t)seg * 8) = rv;
}

// ---- clean m97-structure GEMM: A=Abl[16384][3072], B=wm2[1024][3072], out += bias ----
__global__ __launch_bounds__(256) void gemm2_kernel(
    const unsigned short* __restrict__ A, const unsigned short* __restrict__ Bw,
    const float* __restrict__ b_conv, float* __restrict__ out){
  __shared__ __align__(16) unsigned short As[128 * 64];
  __shared__ __align__(16) unsigned short Bs[128 * 64];
  int wg = blockIdx.x;
  int swz = (wg & 7) * 128 + (wg >> 3);       // 1024 % 8 == 0: bijective XCD swizzle
  int ntile = swz & 7, mtile = swz >> 3;
  int m0 = mtile * 128, n0 = ntile * 128;
  int tid = threadIdx.x, lane = tid & 63, wv = tid >> 6;
  int wr = wv >> 1, wc = wv & 1;
  f32x4 acc[4][4];
  #pragma unroll
  for (int i = 0; i < 4; i++)
    #pragma unroll
    for (int j = 0; j < 4; j++) acc[i][j] = (f32x4){0.f, 0.f, 0.f, 0.f};

  const unsigned short* Ab = A  + (size_t)m0 * 3072;
  const unsigned short* Bb = Bw + (size_t)n0 * 3072;

  for (int c0 = 0; c0 < 3072; c0 += 64){
    #pragma unroll
    for (int it = 0; it < 4; ++it){
      int chunk = it * 4 + wv;                 // 0..15
      int row = chunk * 8 + (lane >> 3);       // 0..127
      size_t go = (size_t)row * 3072 + c0 + (lane & 7) * 8;
      async16(Ab + go, (char*)As + chunk * 1024);
      async16(Bb + go, (char*)Bs + chunk * 1024);
    }
    __syncthreads();
    #pragma unroll
    for (int kk = 0; kk < 2; ++kk){
      int ko = kk * 32 + (lane >> 4) * 8;
      bf16x8 af[4], bfr[4];
      #pragma unroll
      for (int mi = 0; mi < 4; mi++)
        af[mi] = *(const bf16x8*)&As[(wr * 64 + mi * 16 + (lane & 15)) * 64 + ko];
      #pragma unroll
      for (int ni = 0; ni < 4; ni++)
        bfr[ni] = *(const bf16x8*)&Bs[(wc * 64 + ni * 16 + (lane & 15)) * 64 + ko];
      #pragma unroll
      for (int mi = 0; mi < 4; mi++)
        #pragma unroll
        for (int ni = 0; ni < 4; ni++)
          acc[mi][ni] = __builtin_amdgcn_mfma_f32_16x16x32_bf16(af[mi], bfr[ni], acc[mi][ni], 0, 0, 0);
    }
    __syncthreads();
  }
  #pragma unroll
  for (int ni = 0; ni < 4; ni++){
    int n = n0 + wc * 64 + ni * 16 + (lane & 15);
    float bc = b_conv[n];
    #pragma unroll
    for (int mi = 0; mi < 4; mi++){
      int mr = m0 + wr * 64 + mi * 16 + (lane >> 4) * 4;
      f32x4 v = acc[mi][ni];
      #pragma unroll
      for (int j = 0; j < 4; j++)
        out[(size_t)(mr + j) * NO + n] = v[j] + bc;
    }
  }
}

// ---- fallback fused gather-blend GEMM (round-1, adapted to wm2 layout) ----
__global__ __launch_bounds__(256) void gemm_fused_kernel(
    const unsigned short* __restrict__ atr, const unsigned short* __restrict__ wm2,
    const int* __restrict__ i0a, const int* __restrict__ i1a, const float* __restrict__ tya,
    const float* __restrict__ b_conv, float* __restrict__ out){
  __shared__ __align__(16) unsigned short As[128 * 64];
  __shared__ __align__(16) unsigned short Bs[128 * 64];
  int wg = blockIdx.x;
  int swz = (wg & 7) * 128 + (wg >> 3);
  int ntile = swz & 7, mtile = swz >> 3;
  int m0 = mtile * 128, n0 = ntile * 128;
  int b = m0 >> 9;
  int tid = threadIdx.x, lane = tid & 63, wv = tid >> 6;
  int wr = wv >> 1, wc = wv & 1;
  int arow = tid >> 3, aseg = tid & 7;
  f32x4 acc[4][4];
  #pragma unroll
  for (int i = 0; i < 4; i++)
    #pragma unroll
    for (int j = 0; j < 4; j++) acc[i][j] = (f32x4){0.f, 0.f, 0.f, 0.f};
  const size_t atrb = (size_t)b * NT * NC;
  for (int k = 0; k < 3; k++){
    const unsigned short* s0[4]; const unsigned short* s1[4]; float tw[4];
    #pragma unroll
    for (int q = 0; q < 4; q++){
      int m = m0 + q * 32 + arow;
      int idx = m * 3 + k;
      s0[q] = atr + atrb + (size_t)i0a[idx] * NC + aseg * 8;
      s1[q] = atr + atrb + (size_t)i1a[idx] * NC + aseg * 8;
      tw[q] = tya[idx];
    }
    const unsigned short* wkb = wm2 + (size_t)n0 * 3072 + (size_t)k * 1024;
    for (int c0 = 0; c0 < 1024; c0 += 64){
      #pragma unroll
      for (int it = 0; it < 4; ++it){
        int chunk = it * 4 + wv;
        int brow = chunk * 8 + (lane >> 3);
        async16(wkb + (size_t)brow * 3072 + c0 + (lane & 7) * 8, (char*)Bs + chunk * 1024);
      }
      #pragma unroll
      for (int q = 0; q < 4; q++){
        uint4 v0 = *(const uint4*)(s0[q] + c0);
        uint4 v1 = *(const uint4*)(s1[q] + c0);
        float t = tw[q];
        uint4 rv;
        rv.x = blend_pack(v0.x, v1.x, t);
        rv.y = blend_pack(v0.y, v1.y, t);
        rv.z = blend_pack(v0.z, v1.z, t);
        rv.w = blend_pack(v0.w, v1.w, t);
        *(uint4*)&As[(q * 32 + arow) * 64 + aseg * 8] = rv;
      }
      __syncthreads();
      #pragma unroll
      for (int kk = 0; kk < 2; ++kk){
        int ko = kk * 32 + (lane >> 4) * 8;
        bf16x8 af[4], bfr[4];
        #pragma unroll
        for (int mi = 0; mi < 4; mi++)
          af[mi] = *(const bf16x8*)&As[(wr * 64 + mi * 16 + (lane & 15)) * 64 + ko];
        #pragma unroll
        for (int ni = 0; ni < 4; ni++)
          bfr[ni] = *(const bf16x8*)&Bs[(wc * 64 + ni * 16 + (lane & 15)) * 64 + ko];
        #pragma unroll
        for (int mi = 0; mi < 4; mi++)
          #pragma unroll
          for (int ni = 0; ni < 4; ni++)
            acc[mi][ni] = __builtin_amdgcn_mfma_f32_16x16x32_bf16(af[mi], bfr[ni], acc[mi][ni], 0, 0, 0);
      }
      __syncthreads();
    }
  }
  #pragma unroll
  for (int ni = 0; ni < 4; ni++){
    int n = n0 + wc * 64 + ni * 16 + (lane & 15);
    float bc = b_conv[n];
    #pragma unroll
    for (int mi = 0; mi < 4; mi++){
      int mr = m0 + wr * 64 + mi * 16 + (lane >> 4) * 4;
      f32x4 v = acc[mi][ni];
      #pragma unroll
      for (int j = 0; j < 4; j++)
        out[(size_t)(mr + j) * NO + n] = v[j] + bc;
    }
  }
}

extern "C" void kernel_launch(void* const* d_in, const int* in_sizes, int n_in,
                              void* d_out, int out_size, void* d_ws, size_t ws_size,
                              hipStream_t stream){
  (void)in_sizes; (void)n_in; (void)out_size;
  const float* x      = (const float*)d_in[0];
  const float* w_off  = (const float*)d_in[1];
  const float* b_off  = (const float*)d_in[2];
  const float* w_conv = (const float*)d_in[3];
  const float* b_conv = (const float*)d_in[4];
  float* out = (float*)d_out;

  char* ws = (char*)d_ws;
  unsigned short* atr = (unsigned short*)ws;                      // 32 MB   (B,T,C) bf16
  int*   i0a = (int*)  (ws + 33554432);                           // 192 KB
  int*   i1a = (int*)  (ws + 33554432 + 196608);
  float* tya = (float*)(ws + 33554432 + 393216);
  unsigned short* wm2 = (unsigned short*)(ws + 34603008);         // 6 MB    (o, k*1024+c) bf16
  unsigned short* Abl = (unsigned short*)(ws + 40894464);         // 96 MB   (m, k*1024+c) bf16
  const size_t need = 40894464u + 100663296u;                     // ~135 MB

  hipLaunchKernelGGL(transpose_kernel, dim3(NT / 64, NC / 64, NB), dim3(256), 0, stream, x, atr);
  hipLaunchKernelGGL(offsets_kernel,  dim3(NT / 64, NB),          dim3(256), 0, stream,
                     x, w_off, b_off, i0a, i1a, tya);
  hipLaunchKernelGGL(wmix_kernel,     dim3((1024 * 1024) / 256),  dim3(256), 0, stream, w_conv, wm2);

  if (ws_size >= need){
    hipLaunchKernelGGL(blend_kernel, dim3(16384 / 2, 3), dim3(256), 0, stream,
                       atr, i0a, i1a, tya, Abl);
    hipLaunchKernelGGL(gemm2_kernel, dim3((16384 / 128) * (1024 / 128)), dim3(256), 0, stream,
                       Abl, wm2, b_conv, out);
  } else {
    hipLaunchKernelGGL(gemm_fused_kernel, dim3((16384 / 128) * (1024 / 128)), dim3(256), 0, stream,
                       atr, wm2, i0a, i1a, tya, b_conv, out);
  }
}

// Round 3
// 219.965 us; speedup vs baseline: 1.5620x; 1.2766x over previous
//
#include <hip/hip_runtime.h>

#define NB 32
#define NC 1024
#define NT 512
#define NO 1024
#define KTILES 48   // 3072 / 64

typedef __attribute__((ext_vector_type(8))) short bf16x8;
typedef __attribute__((ext_vector_type(4))) float f32x4;

#define FENCE asm volatile("" ::: "memory")
#define BAR do{ FENCE; __builtin_amdgcn_s_barrier(); FENCE; }while(0)
#define LGKM0 asm volatile("s_waitcnt lgkmcnt(0)" ::: "memory")

__device__ __forceinline__ unsigned short f2bf(float f){
  unsigned int i = __float_as_uint(f);
  i += 0x7fffu + ((i >> 16) & 1u);
  return (unsigned short)(i >> 16);
}

__device__ __forceinline__ unsigned int blend_pack(unsigned int u0, unsigned int u1, float t){
  float a0 = __uint_as_float(u0 << 16);
  float a1 = __uint_as_float(u0 & 0xffff0000u);
  float b0 = __uint_as_float(u1 << 16);
  float b1 = __uint_as_float(u1 & 0xffff0000u);
  float r0 = fmaf(t, b0 - a0, a0);
  float r1 = fmaf(t, b1 - a1, a1);
  return (unsigned int)f2bf(r0) | (((unsigned int)f2bf(r1)) << 16);
}

__device__ __forceinline__ void async16(const void* g, void* l){
  __builtin_amdgcn_global_load_lds((const __attribute__((address_space(1))) void*)g,
                                   (__attribute__((address_space(3))) void*)l, 16, 0, 0);
}

// ---- transpose: x (B,C,T) f32 -> atr (B,T,C) bf16 ----
__global__ __launch_bounds__(256) void transpose_kernel(const float* __restrict__ x,
                                                        unsigned short* __restrict__ atr){
  __shared__ float tile[64][65];
  int b = blockIdx.z, c0 = blockIdx.y * 64, t0 = blockIdx.x * 64;
  int tx = threadIdx.x & 63, wy = threadIdx.x >> 6;
  const float* xp = x + ((size_t)b * NC + c0) * NT + t0;
  #pragma unroll
  for (int i = 0; i < 16; i++){ int cl = wy * 16 + i; tile[cl][tx] = xp[(size_t)cl * NT + tx]; }
  __syncthreads();
  int p = threadIdx.x & 31, r = threadIdx.x >> 5;
  unsigned int* dst = (unsigned int*)(atr + ((size_t)b * NT + t0) * NC + c0);
  #pragma unroll
  for (int i = 0; i < 8; i++){
    int tl = r * 8 + i;
    unsigned int lo = f2bf(tile[2 * p][tl]);
    unsigned int hi = f2bf(tile[2 * p + 1][tl]);
    dst[(size_t)tl * (NC / 2) + p] = lo | (hi << 16);
  }
}

// ---- offset conv (fp32) + grid-sample index/weight precompute ----
__global__ __launch_bounds__(256) void offsets_kernel(const float* __restrict__ x,
    const float* __restrict__ w_off, const float* __restrict__ b_off,
    int* __restrict__ i0a, int* __restrict__ i1a, float* __restrict__ tya){
  __shared__ float red[4][64][3];
  int b = blockIdx.y, t0 = blockIdx.x * 64;
  int tl = threadIdx.x & 63, cs = threadIdx.x >> 6;
  int t = t0 + tl;
  const float* xb = x + (size_t)b * NC * NT;
  float a0 = 0.f, a1 = 0.f, a2 = 0.f;
  for (int c = cs * 256; c < (cs + 1) * 256; ++c){
    const float* xr = xb + (size_t)c * NT;
    float xm = (t > 0)      ? xr[t - 1] : 0.f;
    float xc = xr[t];
    float xq = (t < NT - 1) ? xr[t + 1] : 0.f;
    const float* wr = w_off + (size_t)c * 3;
    a0 += xm * wr[0]    + xc * wr[1]    + xq * wr[2];
    a1 += xm * wr[3072] + xc * wr[3073] + xq * wr[3074];
    a2 += xm * wr[6144] + xc * wr[6145] + xq * wr[6146];
  }
  red[cs][tl][0] = a0; red[cs][tl][1] = a1; red[cs][tl][2] = a2;
  __syncthreads();
  if (threadIdx.x < 64){
    int tt = t0 + (int)threadIdx.x;
    #pragma unroll
    for (int o = 0; o < 3; o++){
      float p = red[0][threadIdx.x][o] + red[1][threadIdx.x][o] +
                red[2][threadIdx.x][o] + red[3][threadIdx.x][o] + b_off[o];
      float base = (float)tt / 511.0f * 2.0f - 1.0f;
      float g = base + (float)(o - 1) * (float)(2.0 / 511.0) + p;
      g = fminf(1.0f, fmaxf(-1.0f, g));
      float py = ((g + 1.0f) * 512.0f - 1.0f) * 0.5f;
      float y0 = floorf(py);
      float tyv = py - y0;
      int i0 = (int)y0;
      int i0c = min(max(i0, 0), NT - 1);
      int i1c = min(max(i0 + 1, 0), NT - 1);
      int m = b * NT + tt;
      i0a[m * 3 + o] = i0c; i1a[m * 3 + o] = i1c; tya[m * 3 + o] = tyv;
    }
  }
}

// ---- fold data-independent x-blend into weights: wm2[o][k*1024+c] (bf16, LDK=3072) ----
__global__ __launch_bounds__(256) void wmix_kernel(const float* __restrict__ w_conv,
                                                   unsigned short* __restrict__ wm2){
  int gid = blockIdx.x * 256 + threadIdx.x;
  int o = gid >> 10, c = gid & 1023;
  const float ratio = (float)(1024.0 / 1023.0);
  float acc0 = 0.f, acc1 = 0.f, acc2 = 0.f;
  int wlo = (c > 2) ? c - 2 : 0;
  int whi = (c < 1021) ? c + 2 : 1023;
  for (int w = wlo; w <= whi; ++w){
    float px = (float)w * ratio - 0.5f;
    float x0 = floorf(px);
    float tx = px - x0;
    int i0 = (int)x0;
    int i0c = min(max(i0, 0), 1023);
    int i1c = min(max(i0 + 1, 0), 1023);
    float s = ((i0c == c) ? (1.0f - tx) : 0.f) + ((i1c == c) ? tx : 0.f);
    if (s != 0.f){
      const float* wc = w_conv + ((size_t)o * 1024 + w) * 3;
      acc0 += s * wc[0]; acc1 += s * wc[1]; acc2 += s * wc[2];
    }
  }
  size_t base = (size_t)o * 3072 + c;
  wm2[base]        = f2bf(acc0);
  wm2[base + 1024] = f2bf(acc1);
  wm2[base + 2048] = f2bf(acc2);
}

// ---- materialize blended A: Abl[m][k*1024+c] bf16 (96 MB) ----
__global__ __launch_bounds__(256) void blend_kernel(
    const unsigned short* __restrict__ atr, const int* __restrict__ i0a,
    const int* __restrict__ i1a, const float* __restrict__ tya,
    unsigned short* __restrict__ Abl){
  int k = blockIdx.y;
  int row = blockIdx.x * 2 + (threadIdx.x >> 7);
  int seg = threadIdx.x & 127;
  int idx = row * 3 + k;
  int b = row >> 9;
  const unsigned short* base = atr + (size_t)b * NT * NC;
  const uint4* r0 = (const uint4*)(base + (size_t)i0a[idx] * NC);
  const uint4* r1 = (const uint4*)(base + (size_t)i1a[idx] * NC);
  float t = tya[idx];
  uint4 v0 = r0[seg], v1 = r1[seg], rv;
  rv.x = blend_pack(v0.x, v1.x, t);
  rv.y = blend_pack(v0.y, v1.y, t);
  rv.z = blend_pack(v0.z, v1.z, t);
  rv.w = blend_pack(v0.w, v1.w, t);
  *(uint4*)(Abl + (size_t)row * 3072 + (size_t)k * 1024 + (size_t)seg * 8) = rv;
}

// ---- stage one 128x64 half-tile via global_load_lds, inverse-swizzled source ----
// LDS (row r, 16B-slot s) receives global slot s^(r&7); read side XORs the same.
__device__ __forceinline__ void stage_half(const unsigned short* __restrict__ src,
                                           unsigned short* Lbase, int row0, int q,
                                           int w, int lane){
  int l3 = lane >> 3, l7 = lane & 7;
  int swc = ((l7 ^ l3) << 3);            // swizzled element col within 64
  #pragma unroll
  for (int i = 0; i < 2; i++){
    int ci = i * 8 + w;                  // chunk 0..15, 8 rows each
    const unsigned short* g = src + (size_t)(row0 + ci * 8 + l3) * 3072 + q * 64 + swc;
    async16(g, Lbase + ci * 512);        // 1 KB per wave-issue, linear dest
  }
}

// ---- 256x256 8-phase GEMM (T2+T3+T4+T5): A=Abl[16384][3072], B=wm2[1024][3072] ----
__global__ __launch_bounds__(512, 2) void gemm8_kernel(
    const unsigned short* __restrict__ A, const unsigned short* __restrict__ Bw,
    const float* __restrict__ b_conv, float* __restrict__ out){
  // LDS element map (ushort): dbuf d: d*32768 | A: half h at h*8192 | B: 16384 + h*8192
  __shared__ __align__(16) unsigned short L[65536];

  int wg = blockIdx.x;
  int swz = (wg & 7) * 32 + (wg >> 3);          // 256 wg, bijective XCD swizzle
  int mtile = swz >> 2, ntile = swz & 3;        // consecutive same-XCD wgs share mtile
  int m0 = mtile * 256, n0 = ntile * 256;
  int tid = threadIdx.x, lane = tid & 63, w = tid >> 6;   // 8 waves
  int wm_ = w >> 2, wn_ = w & 3;                // 2 (M) x 4 (N)
  int lq = lane & 15, q4 = lane >> 4;
  int sl0 = (q4 ^ (lq & 7)) << 3;               // swizzled elem col, k-step 0
  int sl1 = ((4 + q4) ^ (lq & 7)) << 3;         // k-step 1
  int hb = wn_ >> 1, nb = (wn_ & 1) * 64;       // this wave's B half / local base

  f32x4 acc[8][4];
  #pragma unroll
  for (int i = 0; i < 8; i++)
    #pragma unroll
    for (int j = 0; j < 4; j++) acc[i][j] = (f32x4){0.f, 0.f, 0.f, 0.f};

  // prologue: tile0 (A0,A1,B0,B1) + tile1 (B0,B1); wait so tile0 landed
  stage_half(A,  &L[0],                 m0,       0, w, lane);
  stage_half(A,  &L[8192],              m0 + 128, 0, w, lane);
  stage_half(Bw, &L[16384],             n0,       0, w, lane);
  stage_half(Bw, &L[16384 + 8192],      n0 + 128, 0, w, lane);
  stage_half(Bw, &L[32768 + 16384],        n0,       1, w, lane);
  stage_half(Bw, &L[32768 + 16384 + 8192], n0 + 128, 1, w, lane);
  asm volatile("s_waitcnt vmcnt(4)" ::: "memory");
  BAR;

  bf16x8 aA[4][2], bB[4][2];

  for (int t = 0; t < KTILES; ++t){
    int c = (t & 1) * 32768;
    int cn = ((t + 1) & 1) * 32768;
    const unsigned short* LA = &L[c + wm_ * 8192];
    const unsigned short* LB = &L[c + 16384 + hb * 8192];

    // ---- P1: read A(mh0) 8x + B(nf0,1) 4x; stage A(t+1,h0); MFMA quad(mh0, np0)
    #pragma unroll
    for (int mf = 0; mf < 4; mf++){
      int r = mf * 16 + lq;
      aA[mf][0] = *(const bf16x8*)&LA[r * 64 + sl0];
      aA[mf][1] = *(const bf16x8*)&LA[r * 64 + sl1];
    }
    #pragma unroll
    for (int nf = 0; nf < 2; nf++){
      int r = nb + nf * 16 + lq;
      bB[nf][0] = *(const bf16x8*)&LB[r * 64 + sl0];
      bB[nf][1] = *(const bf16x8*)&LB[r * 64 + sl1];
    }
    if (t + 1 < KTILES) stage_half(A, &L[cn], m0, t + 1, w, lane);
    BAR; LGKM0;
    __builtin_amdgcn_s_setprio(1);
    #pragma unroll
    for (int mf = 0; mf < 4; mf++)
      #pragma unroll
      for (int nf = 0; nf < 2; nf++){
        acc[mf][nf] = __builtin_amdgcn_mfma_f32_16x16x32_bf16(aA[mf][0], bB[nf][0], acc[mf][nf], 0, 0, 0);
        acc[mf][nf] = __builtin_amdgcn_mfma_f32_16x16x32_bf16(aA[mf][1], bB[nf][1], acc[mf][nf], 0, 0, 0);
      }
    __builtin_amdgcn_s_setprio(0);
    BAR;

    // ---- P2: read B(nf2,3); stage A(t+1,h1); MFMA quad(mh0, np1)
    #pragma unroll
    for (int nf = 2; nf < 4; nf++){
      int r = nb + nf * 16 + lq;
      bB[nf][0] = *(const bf16x8*)&LB[r * 64 + sl0];
      bB[nf][1] = *(const bf16x8*)&LB[r * 64 + sl1];
    }
    if (t + 1 < KTILES) stage_half(A, &L[cn + 8192], m0 + 128, t + 1, w, lane);
    BAR; LGKM0;
    __builtin_amdgcn_s_setprio(1);
    #pragma unroll
    for (int mf = 0; mf < 4; mf++)
      #pragma unroll
      for (int nf = 2; nf < 4; nf++){
        acc[mf][nf] = __builtin_amdgcn_mfma_f32_16x16x32_bf16(aA[mf][0], bB[nf][0], acc[mf][nf], 0, 0, 0);
        acc[mf][nf] = __builtin_amdgcn_mfma_f32_16x16x32_bf16(aA[mf][1], bB[nf][1], acc[mf][nf], 0, 0, 0);
      }
    __builtin_amdgcn_s_setprio(0);
    BAR;

    // ---- P3: read A(mh1); stage B(t+2,h0) -> same dbuf as t (reads done P2); MFMA (mh1, np1)
    #pragma unroll
    for (int mf = 0; mf < 4; mf++){
      int r = 64 + mf * 16 + lq;
      aA[mf][0] = *(const bf16x8*)&LA[r * 64 + sl0];
      aA[mf][1] = *(const bf16x8*)&LA[r * 64 + sl1];
    }
    if (t + 2 < KTILES) stage_half(Bw, &L[c + 16384], n0, t + 2, w, lane);
    BAR; LGKM0;
    __builtin_amdgcn_s_setprio(1);
    #pragma unroll
    for (int mf = 0; mf < 4; mf++)
      #pragma unroll
      for (int nf = 2; nf < 4; nf++){
        acc[4 + mf][nf] = __builtin_amdgcn_mfma_f32_16x16x32_bf16(aA[mf][0], bB[nf][0], acc[4 + mf][nf], 0, 0, 0);
        acc[4 + mf][nf] = __builtin_amdgcn_mfma_f32_16x16x32_bf16(aA[mf][1], bB[nf][1], acc[4 + mf][nf], 0, 0, 0);
      }
    __builtin_amdgcn_s_setprio(0);
    BAR;

    // ---- P4: stage B(t+2,h1); MFMA (mh1, np0); boundary counted vmcnt
    if (t + 2 < KTILES) stage_half(Bw, &L[c + 16384 + 8192], n0 + 128, t + 2, w, lane);
    BAR;
    __builtin_amdgcn_s_setprio(1);
    #pragma unroll
    for (int mf = 0; mf < 4; mf++)
      #pragma unroll
      for (int nf = 0; nf < 2; nf++){
        acc[4 + mf][nf] = __builtin_amdgcn_mfma_f32_16x16x32_bf16(aA[mf][0], bB[nf][0], acc[4 + mf][nf], 0, 0, 0);
        acc[4 + mf][nf] = __builtin_amdgcn_mfma_f32_16x16x32_bf16(aA[mf][1], bB[nf][1], acc[4 + mf][nf], 0, 0, 0);
      }
    __builtin_amdgcn_s_setprio(0);
    if (t + 2 < KTILES)      { asm volatile("s_waitcnt vmcnt(4)" ::: "memory"); }
    else if (t + 1 < KTILES) { asm volatile("s_waitcnt vmcnt(0)" ::: "memory"); }
    BAR;
  }

  // ---- epilogue: C/D layout col=lane&15, row=(lane>>4)*4+j
  #pragma unroll
  for (int nf = 0; nf < 4; nf++){
    int n = n0 + wn_ * 64 + nf * 16 + lq;
    float bc = b_conv[n];
    #pragma unroll
    for (int mh = 0; mh < 2; mh++)
      #pragma unroll
      for (int mf = 0; mf < 4; mf++){
        int mr = m0 + wm_ * 128 + mh * 64 + mf * 16 + q4 * 4;
        f32x4 v = acc[mh * 4 + mf][nf];
        #pragma unroll
        for (int j = 0; j < 4; j++)
          out[(size_t)(mr + j) * NO + n] = v[j] + bc;
      }
  }
}

extern "C" void kernel_launch(void* const* d_in, const int* in_sizes, int n_in,
                              void* d_out, int out_size, void* d_ws, size_t ws_size,
                              hipStream_t stream){
  (void)in_sizes; (void)n_in; (void)out_size; (void)ws_size;
  const float* x      = (const float*)d_in[0];
  const float* w_off  = (const float*)d_in[1];
  const float* b_off  = (const float*)d_in[2];
  const float* w_conv = (const float*)d_in[3];
  const float* b_conv = (const float*)d_in[4];
  float* out = (float*)d_out;

  char* ws = (char*)d_ws;
  unsigned short* atr = (unsigned short*)ws;                      // 32 MB   (B,T,C) bf16
  int*   i0a = (int*)  (ws + 33554432);                           // 192 KB
  int*   i1a = (int*)  (ws + 33554432 + 196608);
  float* tya = (float*)(ws + 33554432 + 393216);
  unsigned short* wm2 = (unsigned short*)(ws + 34603008);         // 6 MB    (o, k*1024+c) bf16
  unsigned short* Abl = (unsigned short*)(ws + 40894464);         // 96 MB   (m, k*1024+c) bf16

  hipLaunchKernelGGL(transpose_kernel, dim3(NT / 64, NC / 64, NB), dim3(256), 0, stream, x, atr);
  hipLaunchKernelGGL(offsets_kernel,  dim3(NT / 64, NB),          dim3(256), 0, stream,
                     x, w_off, b_off, i0a, i1a, tya);
  hipLaunchKernelGGL(wmix_kernel,     dim3((1024 * 1024) / 256),  dim3(256), 0, stream, w_conv, wm2);
  hipLaunchKernelGGL(blend_kernel,    dim3(16384 / 2, 3),         dim3(256), 0, stream,
                     atr, i0a, i1a, tya, Abl);
  hipLaunchKernelGGL(gemm8_kernel,    dim3((16384 / 256) * (1024 / 256)), dim3(512), 0, stream,
                     Abl, wm2, b_conv, out);
}

// Round 4
// 215.539 us; speedup vs baseline: 1.5940x; 1.0205x over previous
//
#include <hip/hip_runtime.h>

#define NB 32
#define NC 1024
#define NT 512
#define NO 1024
#define KTILES 48   // 3072 / 64

typedef __attribute__((ext_vector_type(8))) short bf16x8;
typedef __attribute__((ext_vector_type(4))) float f32x4;

#define FENCE asm volatile("" ::: "memory")
#define BAR do{ FENCE; __builtin_amdgcn_s_barrier(); FENCE; }while(0)
#define LGKM0 asm volatile("s_waitcnt lgkmcnt(0)" ::: "memory")

__device__ __forceinline__ unsigned short f2bf(float f){
  unsigned int i = __float_as_uint(f);
  i += 0x7fffu + ((i >> 16) & 1u);
  return (unsigned short)(i >> 16);
}

__device__ __forceinline__ unsigned int blend_pack(unsigned int u0, unsigned int u1, float t){
  float a0 = __uint_as_float(u0 << 16);
  float a1 = __uint_as_float(u0 & 0xffff0000u);
  float b0 = __uint_as_float(u1 << 16);
  float b1 = __uint_as_float(u1 & 0xffff0000u);
  float r0 = fmaf(t, b0 - a0, a0);
  float r1 = fmaf(t, b1 - a1, a1);
  return (unsigned int)f2bf(r0) | (((unsigned int)f2bf(r1)) << 16);
}

__device__ __forceinline__ void async16(const void* g, void* l){
  __builtin_amdgcn_global_load_lds((const __attribute__((address_space(1))) void*)g,
                                   (__attribute__((address_space(3))) void*)l, 16, 0, 0);
}

// ---- fused transpose + offset-conv partials ----
// x (B,C,T) f32 -> atr (B,T,C) bf16 ; part[(m*3+o)*16 + cblk] = partial conv sums
__global__ __launch_bounds__(256) void transpose_off_kernel(const float* __restrict__ x,
    const float* __restrict__ w_off, unsigned short* __restrict__ atr,
    float* __restrict__ part){
  __shared__ float tile[64][67];   // col 0 = t0-1 halo, 1..64 = main, 65 = t0+64 halo
  __shared__ float wsh[64][9];
  __shared__ float red[4][64][3];
  int b = blockIdx.z, c0 = blockIdx.y * 64, t0 = blockIdx.x * 64;
  int tx = threadIdx.x & 63, wy = threadIdx.x >> 6;
  const float* xp = x + ((size_t)b * NC + c0) * NT + t0;
  #pragma unroll
  for (int i = 0; i < 16; i++){ int cl = wy * 16 + i; tile[cl][1 + tx] = xp[(size_t)cl * NT + tx]; }
  if (threadIdx.x < 64){
    tile[tx][0]  = (t0 > 0)       ? xp[(size_t)tx * NT - 1]  : 0.f;
  } else if (threadIdx.x < 128){
    tile[tx][65] = (t0 + 64 < NT) ? xp[(size_t)tx * NT + 64] : 0.f;
  }
  for (int i = threadIdx.x; i < 576; i += 256){
    int c = i / 9, r = i % 9;
    wsh[c][r] = w_off[(size_t)(r / 3) * 3072 + (size_t)(c0 + c) * 3 + (r % 3)];
  }
  __syncthreads();
  // transpose write
  int p = threadIdx.x & 31, r2 = threadIdx.x >> 5;
  unsigned int* dst = (unsigned int*)(atr + ((size_t)b * NT + t0) * NC + c0);
  #pragma unroll
  for (int i = 0; i < 8; i++){
    int tl = r2 * 8 + i;
    unsigned int lo = f2bf(tile[2 * p][1 + tl]);
    unsigned int hi = f2bf(tile[2 * p + 1][1 + tl]);
    dst[(size_t)tl * (NC / 2) + p] = lo | (hi << 16);
  }
  // partial conv: thread (tx, cs=wy) sums 16 channels
  float s0 = 0.f, s1 = 0.f, s2 = 0.f;
  #pragma unroll 4
  for (int i = 0; i < 16; i++){
    int c = wy * 16 + i;
    float xm = tile[c][tx], xc = tile[c][1 + tx], xq = tile[c][2 + tx];
    s0 += xm * wsh[c][0] + xc * wsh[c][1] + xq * wsh[c][2];
    s1 += xm * wsh[c][3] + xc * wsh[c][4] + xq * wsh[c][5];
    s2 += xm * wsh[c][6] + xc * wsh[c][7] + xq * wsh[c][8];
  }
  red[wy][tx][0] = s0; red[wy][tx][1] = s1; red[wy][tx][2] = s2;
  __syncthreads();
  if (threadIdx.x < 192){
    int tl = threadIdx.x & 63, o = threadIdx.x >> 6;
    float v = red[0][tl][o] + red[1][tl][o] + red[2][tl][o] + red[3][tl][o];
    size_t m = (size_t)b * NT + t0 + tl;
    part[(m * 3 + o) * 16 + blockIdx.y] = v;
  }
}

// ---- reduce partials + grid-sample index/weight computation ----
__global__ __launch_bounds__(256) void index_kernel(const float* __restrict__ part,
    const float* __restrict__ b_off, int* __restrict__ i0a, int* __restrict__ i1a,
    float* __restrict__ tya){
  int gid = blockIdx.x * 256 + threadIdx.x;    // 32*512*3 = 49152 exact
  int o = gid % 3, m = gid / 3, tt = m & 511;
  const float* pp = part + (size_t)gid * 16;
  float p = b_off[o];
  #pragma unroll
  for (int i = 0; i < 16; i++) p += pp[i];
  float base = (float)tt / 511.0f * 2.0f - 1.0f;
  float g = base + (float)(o - 1) * (float)(2.0 / 511.0) + p;
  g = fminf(1.0f, fmaxf(-1.0f, g));
  float py = ((g + 1.0f) * 512.0f - 1.0f) * 0.5f;
  float y0 = floorf(py);
  int i0 = (int)y0;
  i0a[gid] = min(max(i0, 0), NT - 1);
  i1a[gid] = min(max(i0 + 1, 0), NT - 1);
  tya[gid] = py - y0;
}

// ---- fold data-independent x-blend into weights: wm2[o][k*1024+c] (bf16, LDK=3072) ----
__global__ __launch_bounds__(256) void wmix_kernel(const float* __restrict__ w_conv,
                                                   unsigned short* __restrict__ wm2){
  int gid = blockIdx.x * 256 + threadIdx.x;
  int o = gid >> 10, c = gid & 1023;
  const float ratio = (float)(1024.0 / 1023.0);
  float acc0 = 0.f, acc1 = 0.f, acc2 = 0.f;
  int wlo = (c > 2) ? c - 2 : 0;
  int whi = (c < 1021) ? c + 2 : 1023;
  for (int w = wlo; w <= whi; ++w){
    float px = (float)w * ratio - 0.5f;
    float x0 = floorf(px);
    float tx = px - x0;
    int i0 = (int)x0;
    int i0c = min(max(i0, 0), 1023);
    int i1c = min(max(i0 + 1, 0), 1023);
    float s = ((i0c == c) ? (1.0f - tx) : 0.f) + ((i1c == c) ? tx : 0.f);
    if (s != 0.f){
      const float* wc = w_conv + ((size_t)o * 1024 + w) * 3;
      acc0 += s * wc[0]; acc1 += s * wc[1]; acc2 += s * wc[2];
    }
  }
  size_t base = (size_t)o * 3072 + c;
  wm2[base]        = f2bf(acc0);
  wm2[base + 1024] = f2bf(acc1);
  wm2[base + 2048] = f2bf(acc2);
}

// ---- stage one 128x64 B half-tile via global_load_lds, inverse-swizzled source ----
__device__ __forceinline__ void stage_half(const unsigned short* __restrict__ src,
                                           unsigned short* Lbase, int row0, int q,
                                           int w, int lane){
  int l3 = lane >> 3, l7 = lane & 7;
  int swc = ((l7 ^ l3) << 3);
  #pragma unroll
  for (int i = 0; i < 2; i++){
    int ci = i * 8 + w;
    const unsigned short* g = src + (size_t)(row0 + ci * 8 + l3) * 3072 + q * 64 + swc;
    async16(g, Lbase + ci * 512);
  }
}

// blend+write A sub-chunk i (0,1 = half0 chunks w,w+8 ; 2,3 = half1)
#define BLENDW(Lb, i) { \
    float tt_ = mtw[i]; uint4 v0_ = ga0[i], v1_ = ga1[i], rv_; \
    rv_.x = blend_pack(v0_.x, v1_.x, tt_); rv_.y = blend_pack(v0_.y, v1_.y, tt_); \
    rv_.z = blend_pack(v0_.z, v1_.z, tt_); rv_.w = blend_pack(v0_.w, v1_.w, tt_); \
    *(uint4*)&(Lb)[(((i) & 1) ? (w + 8) : w) * 512 + lane * 8] = rv_; }

#define LOADMETA(kk) { \
    _Pragma("unroll") \
    for (int i_ = 0; i_ < 4; i_++){ \
      int row_ = m0 + (i_ >> 1) * 128 + ((i_ & 1) ? r1 : r0); \
      int idx_ = row_ * 3 + (kk); \
      mo0[i_] = (unsigned)i0a[idx_] << 11; \
      mo1[i_] = (unsigned)i1a[idx_] << 11; \
      mtw[i_] = tya[idx_]; } }

#define ISSUEA(q) { \
    int colb_ = ((q) & 15) * 128 + (scol << 1); \
    _Pragma("unroll") \
    for (int i_ = 0; i_ < 4; i_++){ \
      ga0[i_] = *(const uint4*)((const char*)atrb + mo0[i_] + colb_); \
      ga1[i_] = *(const uint4*)((const char*)atrb + mo1[i_] + colb_); } }

// ---- 256x256 8-phase GEMM, A = gather+blend of atr (reg-staged), B = wm2 (gload_lds) ----
__global__ __launch_bounds__(512, 2) void gemm8_kernel(
    const unsigned short* __restrict__ atr, const unsigned short* __restrict__ Bw,
    const int* __restrict__ i0a, const int* __restrict__ i1a, const float* __restrict__ tya,
    const float* __restrict__ b_conv, float* __restrict__ out){
  __shared__ __align__(16) unsigned short L[65536];

  int wg = blockIdx.x;
  int swz = (wg & 7) * 32 + (wg >> 3);
  int mtile = swz >> 2, ntile = swz & 3;
  int m0 = mtile * 256, n0 = ntile * 256;
  int tid = threadIdx.x, lane = tid & 63, w = tid >> 6;
  int wm_ = w >> 2, wn_ = w & 3;
  int lq = lane & 15, q4 = lane >> 4;
  int sl0 = (q4 ^ (lq & 7)) << 3;
  int sl1 = ((4 + q4) ^ (lq & 7)) << 3;
  int hb = wn_ >> 1, nb = (wn_ & 1) * 64;
  int l3 = lane >> 3, l7 = lane & 7;
  int scol = (l7 ^ l3) << 3;
  int r0 = w * 8 + l3, r1 = (w + 8) * 8 + l3;
  const unsigned short* atrb = atr + (size_t)(m0 >> 9) * NT * NC;

  f32x4 acc[8][4];
  #pragma unroll
  for (int i = 0; i < 8; i++)
    #pragma unroll
    for (int j = 0; j < 4; j++) acc[i][j] = (f32x4){0.f, 0.f, 0.f, 0.f};

  unsigned mo0[4], mo1[4]; float mtw[4];
  uint4 ga0[4], ga1[4];

  // prologue: A(0) reg-gather+blend -> buf0 ; B(0),B(1) async
  LOADMETA(0);
  ISSUEA(0);
  BLENDW(&L[0], 0); BLENDW(&L[0], 1);
  BLENDW(&L[8192], 2); BLENDW(&L[8192], 3);
  LGKM0;
  stage_half(Bw, &L[16384],                n0,       0, w, lane);
  stage_half(Bw, &L[16384 + 8192],         n0 + 128, 0, w, lane);
  stage_half(Bw, &L[32768 + 16384],        n0,       1, w, lane);
  stage_half(Bw, &L[32768 + 16384 + 8192], n0 + 128, 1, w, lane);
  asm volatile("s_waitcnt vmcnt(4)" ::: "memory");
  BAR;

  bf16x8 aA[4][2], bB[4][2];

  for (int t = 0; t < KTILES; ++t){
    int c = (t & 1) * 32768;
    int cn = ((t + 1) & 1) * 32768;
    const unsigned short* LA = &L[c + wm_ * 8192];
    const unsigned short* LB = &L[c + 16384 + hb * 8192];

    // ---- P1: ds_read A(mh0)+B(nf0,1); meta reload + issue A(t+1) gathers; MFMA(mh0,np0)
    #pragma unroll
    for (int mf = 0; mf < 4; mf++){
      int r = mf * 16 + lq;
      aA[mf][0] = *(const bf16x8*)&LA[r * 64 + sl0];
      aA[mf][1] = *(const bf16x8*)&LA[r * 64 + sl1];
    }
    #pragma unroll
    for (int nf = 0; nf < 2; nf++){
      int r = nb + nf * 16 + lq;
      bB[nf][0] = *(const bf16x8*)&LB[r * 64 + sl0];
      bB[nf][1] = *(const bf16x8*)&LB[r * 64 + sl1];
    }
    if (t + 1 < KTILES){
      if (((t + 1) & 15) == 0) LOADMETA((t + 1) >> 4);
      ISSUEA(t + 1);
    }
    BAR; LGKM0;
    __builtin_amdgcn_s_setprio(1);
    #pragma unroll
    for (int mf = 0; mf < 4; mf++)
      #pragma unroll
      for (int nf = 0; nf < 2; nf++){
        acc[mf][nf] = __builtin_amdgcn_mfma_f32_16x16x32_bf16(aA[mf][0], bB[nf][0], acc[mf][nf], 0, 0, 0);
        acc[mf][nf] = __builtin_amdgcn_mfma_f32_16x16x32_bf16(aA[mf][1], bB[nf][1], acc[mf][nf], 0, 0, 0);
      }
    __builtin_amdgcn_s_setprio(0);
    BAR;

    // ---- P2: ds_read B(nf2,3); blend+write A(t+1,h0); MFMA(mh0,np1)
    #pragma unroll
    for (int nf = 2; nf < 4; nf++){
      int r = nb + nf * 16 + lq;
      bB[nf][0] = *(const bf16x8*)&LB[r * 64 + sl0];
      bB[nf][1] = *(const bf16x8*)&LB[r * 64 + sl1];
    }
    if (t + 1 < KTILES){ BLENDW(&L[cn], 0); BLENDW(&L[cn], 1); }
    BAR; LGKM0;
    __builtin_amdgcn_s_setprio(1);
    #pragma unroll
    for (int mf = 0; mf < 4; mf++)
      #pragma unroll
      for (int nf = 2; nf < 4; nf++){
        acc[mf][nf] = __builtin_amdgcn_mfma_f32_16x16x32_bf16(aA[mf][0], bB[nf][0], acc[mf][nf], 0, 0, 0);
        acc[mf][nf] = __builtin_amdgcn_mfma_f32_16x16x32_bf16(aA[mf][1], bB[nf][1], acc[mf][nf], 0, 0, 0);
      }
    __builtin_amdgcn_s_setprio(0);
    BAR;

    // ---- P3: ds_read A(mh1); blend+write A(t+1,h1); stage B(t+2,h0); MFMA(mh1,np1)
    #pragma unroll
    for (int mf = 0; mf < 4; mf++){
      int r = 64 + mf * 16 + lq;
      aA[mf][0] = *(const bf16x8*)&LA[r * 64 + sl0];
      aA[mf][1] = *(const bf16x8*)&LA[r * 64 + sl1];
    }
    if (t + 1 < KTILES){ BLENDW(&L[cn + 8192], 2); BLENDW(&L[cn + 8192], 3); }
    if (t + 2 < KTILES) stage_half(Bw, &L[c + 16384], n0, t + 2, w, lane);
    BAR; LGKM0;
    __builtin_amdgcn_s_setprio(1);
    #pragma unroll
    for (int mf = 0; mf < 4; mf++)
      #pragma unroll
      for (int nf = 2; nf < 4; nf++){
        acc[4 + mf][nf] = __builtin_amdgcn_mfma_f32_16x16x32_bf16(aA[mf][0], bB[nf][0], acc[4 + mf][nf], 0, 0, 0);
        acc[4 + mf][nf] = __builtin_amdgcn_mfma_f32_16x16x32_bf16(aA[mf][1], bB[nf][1], acc[4 + mf][nf], 0, 0, 0);
      }
    __builtin_amdgcn_s_setprio(0);
    BAR;

    // ---- P4: stage B(t+2,h1); MFMA(mh1,np0); boundary counted vmcnt
    if (t + 2 < KTILES) stage_half(Bw, &L[c + 16384 + 8192], n0 + 128, t + 2, w, lane);
    BAR;
    __builtin_amdgcn_s_setprio(1);
    #pragma unroll
    for (int mf = 0; mf < 4; mf++)
      #pragma unroll
      for (int nf = 0; nf < 2; nf++){
        acc[4 + mf][nf] = __builtin_amdgcn_mfma_f32_16x16x32_bf16(aA[mf][0], bB[nf][0], acc[4 + mf][nf], 0, 0, 0);
        acc[4 + mf][nf] = __builtin_amdgcn_mfma_f32_16x16x32_bf16(aA[mf][1], bB[nf][1], acc[4 + mf][nf], 0, 0, 0);
      }
    __builtin_amdgcn_s_setprio(0);
    asm volatile("s_waitcnt vmcnt(4)" ::: "memory");
    BAR;
  }

  // ---- epilogue: C/D layout col=lane&15, row=(lane>>4)*4+j
  #pragma unroll
  for (int nf = 0; nf < 4; nf++){
    int n = n0 + wn_ * 64 + nf * 16 + lq;
    float bc = b_conv[n];
    #pragma unroll
    for (int mh = 0; mh < 2; mh++)
      #pragma unroll
      for (int mf = 0; mf < 4; mf++){
        int mr = m0 + wm_ * 128 + mh * 64 + mf * 16 + q4 * 4;
        f32x4 v = acc[mh * 4 + mf][nf];
        #pragma unroll
        for (int j = 0; j < 4; j++)
          out[(size_t)(mr + j) * NO + n] = v[j] + bc;
      }
  }
}

extern "C" void kernel_launch(void* const* d_in, const int* in_sizes, int n_in,
                              void* d_out, int out_size, void* d_ws, size_t ws_size,
                              hipStream_t stream){
  (void)in_sizes; (void)n_in; (void)out_size; (void)ws_size;
  const float* x      = (const float*)d_in[0];
  const float* w_off  = (const float*)d_in[1];
  const float* b_off  = (const float*)d_in[2];
  const float* w_conv = (const float*)d_in[3];
  const float* b_conv = (const float*)d_in[4];
  float* out = (float*)d_out;

  char* ws = (char*)d_ws;
  unsigned short* atr = (unsigned short*)ws;                       // 32 MB  (B,T,C) bf16
  float* part = (float*)(ws + 33554432);                           // 3 MB   partial conv sums
  int*   i0a = (int*)  (ws + 33554432 + 3145728);                  // 192 KB each
  int*   i1a = (int*)  (ws + 33554432 + 3145728 + 196608);
  float* tya = (float*)(ws + 33554432 + 3145728 + 393216);
  unsigned short* wm2 = (unsigned short*)(ws + 33554432 + 3145728 + 589824);  // 6 MB

  hipLaunchKernelGGL(transpose_off_kernel, dim3(NT / 64, NC / 64, NB), dim3(256), 0, stream,
                     x, w_off, atr, part);
  hipLaunchKernelGGL(index_kernel, dim3(49152 / 256), dim3(256), 0, stream,
                     part, b_off, i0a, i1a, tya);
  hipLaunchKernelGGL(wmix_kernel,  dim3((1024 * 1024) / 256), dim3(256), 0, stream, w_conv, wm2);
  hipLaunchKernelGGL(gemm8_kernel, dim3((16384 / 256) * (1024 / 256)), dim3(512), 0, stream,
                     atr, wm2, i0a, i1a, tya, b_conv, out);
}